// Round 1
// baseline (244.073 us; speedup 1.0000x reference)
//
#include <hip/hip_runtime.h>

#define T_TOK 2048
#define HID   1024
#define FFN   2048
#define NEXP  8
#define MAX_SLOTS 24   // sum_e ceil(cnt_e/128) <= 8 + 2048/128 - 1 < 24

typedef __attribute__((ext_vector_type(8))) short bf16x8;
typedef __attribute__((ext_vector_type(4))) float f32x4;

__device__ __forceinline__ short f2bf(float f) {
    unsigned u = __builtin_bit_cast(unsigned, f);
    u = (u + 0x7fffu + ((u >> 16) & 1u)) >> 16;
    return (short)u;
}

__device__ __forceinline__ float gelu_exact(float x) {
    return 0.5f * x * (1.0f + erff(x * 0.70710678118654752f));
}

// async 16B global -> LDS DMA. LDS dest: wave-uniform base + lane*16.
__device__ __forceinline__ void async_cp16(const short* g, short* l) {
    __builtin_amdgcn_global_load_lds(
        (const __attribute__((address_space(1))) unsigned int*)g,
        (__attribute__((address_space(3))) unsigned int*)l, 16, 0, 0);
}

// ---- weight transpose body: W[e][K][N] f32 -> tiled bf16 panels -----------
// WT layout: [e][npanel=N/128][kpanel=K/64][kc=8][n=128][k8=8] (8192 shorts/panel)
__device__ __forceinline__ void wtrans_body(
        const float* __restrict__ W, short* __restrict__ WT,
        int K, int N, int e, int kblk, int nblk) {
    int tid = threadIdx.x;
    int w = tid >> 6, l = tid & 63;
    int kb = kblk * 32 + w * 8;               // this wave: 8 k-rows
    int n4 = nblk * 256 + l * 4;              // this lane: 4 n-cols
    const float* src = W + (size_t)e * K * N + (size_t)kb * N + n4;
    float4 v[8];
#pragma unroll
    for (int r = 0; r < 8; r++)
        v[r] = *(const float4*)(src + (size_t)r * N);
    int kpanel = kb >> 6;
    int kc = (kb >> 3) & 7;
    int npanel = n4 >> 7;
    int n_in = n4 & 127;
    int kpanels = K >> 6;
    short* dst = WT + (size_t)e * K * N
               + ((size_t)npanel * kpanels + kpanel) * 8192
               + kc * 1024 + n_in * 8;
#pragma unroll
    for (int j = 0; j < 4; j++) {
        bf16x8 o = {f2bf(((const float*)&v[0])[j]), f2bf(((const float*)&v[1])[j]),
                    f2bf(((const float*)&v[2])[j]), f2bf(((const float*)&v[3])[j]),
                    f2bf(((const float*)&v[4])[j]), f2bf(((const float*)&v[5])[j]),
                    f2bf(((const float*)&v[6])[j]), f2bf(((const float*)&v[7])[j])};
        *(bf16x8*)(dst + j * 8) = o;
    }
}

// ---- fused prep: wtrans W1 | wtrans W2 | xcvt | bucket --------------------
__global__ __launch_bounds__(256) void prep_kernel(
        const float* __restrict__ x, const int* __restrict__ idx,
        const float* __restrict__ W1, const float* __restrict__ W2,
        short* __restrict__ xb,
        short* __restrict__ W1T, short* __restrict__ W2T,
        int* __restrict__ offs, int* __restrict__ cnts,
        int* __restrict__ tokl,
        int* __restrict__ slot_e, int* __restrict__ slot_t0) {
    int bx = blockIdx.x;
    int tid = threadIdx.x;
    if (bx < 2048) {                       // W1: 8e x (32 kblk x 8 nblk)
        int e = bx >> 8, rem = bx & 255;
        wtrans_body(W1, W1T, HID, FFN, e, rem & 31, rem >> 5);
    } else if (bx < 4096) {                // W2: 8e x (64 kblk x 4 nblk)
        int b = bx - 2048;
        int e = b >> 8, rem = b & 255;
        wtrans_body(W2, W2T, FFN, HID, e, rem & 63, rem >> 6);
    } else if (bx < 5120) {                // x f32 -> bf16
        int i = ((bx - 4096) * 256 + tid) * 8;
        float4 v0 = *(const float4*)(x + i);
        float4 v1 = *(const float4*)(x + i + 4);
        bf16x8 r = {f2bf(v0.x), f2bf(v0.y), f2bf(v0.z), f2bf(v0.w),
                    f2bf(v1.x), f2bf(v1.y), f2bf(v1.z), f2bf(v1.w)};
        *(bf16x8*)(xb + i) = r;
    } else {                               // bucket + slot worklist (128/slot)
        __shared__ int c[NEXP], cur[NEXP], o[NEXP];
        if (tid < NEXP) { c[tid] = 0; cur[tid] = 0; }
        __syncthreads();
        for (int t = tid; t < T_TOK; t += 256) atomicAdd(&c[idx[t]], 1);
        __syncthreads();
        if (tid == 0) {
            int s = 0;
            for (int e = 0; e < NEXP; e++) { o[e] = s; s += c[e]; }
            int ns = 0;
            for (int e = 0; e < NEXP; e++)
                for (int t0 = 0; t0 < c[e]; t0 += 128) {
                    slot_e[ns] = e; slot_t0[ns] = t0; ns++;
                }
            for (; ns < MAX_SLOTS; ns++) slot_e[ns] = -1;
        }
        __syncthreads();
        if (tid < NEXP) { offs[tid] = o[tid]; cnts[tid] = c[tid]; }
        for (int t = tid; t < T_TOK; t += 256) {
            int e = idx[t];
            int p = o[e] + atomicAdd(&cur[e], 1);
            tokl[p] = t;
        }
    }
}

// ---- GEMM1: hg = gelu(xb_gathered @ W1T + b1) ------------------------------
// block 128m x 128n, BK=64, 4 waves each 64x64. grid (FFN/128, MAX_SLOTS).
__global__ __launch_bounds__(256) void gemm1_kernel(
        const short* __restrict__ xb, const short* __restrict__ W1T,
        const float* __restrict__ b1,
        const int* __restrict__ offs, const int* __restrict__ cnts,
        const int* __restrict__ tokl,
        const int* __restrict__ slot_e, const int* __restrict__ slot_t0,
        short* __restrict__ hg) {
    int s = blockIdx.y;
    int e = slot_e[s];
    if (e < 0) return;
    int t0 = slot_t0[s], count = cnts[e], off = offs[e];
    int n0 = blockIdx.x * 128;

    __shared__ short As[128 * 64];       // [128m][64k], chunk-rotated rows
    __shared__ short Bs[8 * 128 * 8];    // [8kc][128n][8k] linear panel image
    __shared__ int stok[128];

    int tid = threadIdx.x;
    if (tid < 128) {
        int p = t0 + tid;
        stok[tid] = tokl[off + (p < count ? p : count - 1)];
    }
    __syncthreads();

    int w = tid >> 6, l = tid & 63, l15 = l & 15, quad = l >> 4;
    int wm = (w >> 1) * 64, wn = (w & 1) * 64;
    int lsub = l >> 3, cs = l & 7;

    // A staging: 4 instrs/thread; instr i: row m = w*32+i*8+lsub, chunk slot cs
    const short* gA[4];
    short* lA[4];
#pragma unroll
    for (int i = 0; i < 4; i++) {
        int m = w * 32 + i * 8 + lsub;
        int c = (cs - m) & 7;            // chunk rotation by row
        gA[i] = xb + (size_t)stok[m] * HID + c * 8;
        lA[i] = As + w * 2048 + i * 512 + l * 8;
    }

    // B staging: 4 instrs/thread, linear 16KB panel image
    const short* Bpan = W1T + (size_t)e * (HID * FFN)
                      + (size_t)(n0 >> 7) * ((HID >> 6) * 8192);
    int bo[4];
#pragma unroll
    for (int i = 0; i < 4; i++) bo[i] = (w * 4 + i) * 512 + l * 8;

    f32x4 acc[4][4];
#pragma unroll
    for (int i = 0; i < 4; i++)
#pragma unroll
        for (int j = 0; j < 4; j++) acc[i][j] = (f32x4){0.f, 0.f, 0.f, 0.f};

    for (int kt = 0; kt < HID / 64; kt++) {
        const short* bp = Bpan + (size_t)kt * 8192;
#pragma unroll
        for (int i = 0; i < 4; i++) async_cp16(gA[i], lA[i]);
#pragma unroll
        for (int i = 0; i < 4; i++) async_cp16(bp + bo[i], Bs + bo[i]);
#pragma unroll
        for (int i = 0; i < 4; i++) gA[i] += 64;
        __syncthreads();
#pragma unroll
        for (int kk = 0; kk < 2; kk++) {
            bf16x8 a[4], b[4];
#pragma unroll
            for (int mt = 0; mt < 4; mt++) {
                int m = wm + mt * 16 + l15;
                a[mt] = *(const bf16x8*)&As[m * 64 + (((kk * 4 + quad) + m) & 7) * 8];
            }
#pragma unroll
            for (int nt = 0; nt < 4; nt++) {
                int n = wn + nt * 16 + l15;
                b[nt] = *(const bf16x8*)&Bs[(kk * 4 + quad) * 1024 + n * 8];
            }
#pragma unroll
            for (int mt = 0; mt < 4; mt++)
#pragma unroll
                for (int nt = 0; nt < 4; nt++)
                    acc[mt][nt] = __builtin_amdgcn_mfma_f32_16x16x32_bf16(
                        a[mt], b[nt], acc[mt][nt], 0, 0, 0);
        }
        __syncthreads();
    }

    const float* b1e = b1 + e * FFN + n0;
#pragma unroll
    for (int mt = 0; mt < 4; mt++) {
        int rbase = wm + mt * 16 + quad * 4;
#pragma unroll
        for (int nt = 0; nt < 4; nt++) {
            int coln = wn + nt * 16 + l15;
            float bb = b1e[coln];
#pragma unroll
            for (int r = 0; r < 4; r++) {
                int p = t0 + rbase + r;
                if (p < count)
                    hg[(size_t)(off + p) * FFN + n0 + coln] =
                        f2bf(gelu_exact(acc[mt][nt][r] + bb));
            }
        }
    }
}

// ---- GEMM2: out[tok] = hg_gathered @ W2T + b2  (no split-K, no atomics) ----
// block 128m x 128n, K=2048. grid (HID/128, MAX_SLOTS).
__global__ __launch_bounds__(256) void gemm2_kernel(
        const short* __restrict__ hg, const short* __restrict__ W2T,
        const float* __restrict__ b2,
        const int* __restrict__ offs, const int* __restrict__ cnts,
        const int* __restrict__ tokl,
        const int* __restrict__ slot_e, const int* __restrict__ slot_t0,
        float* __restrict__ out) {
    int s = blockIdx.y;
    int e = slot_e[s];
    if (e < 0) return;
    int t0 = slot_t0[s], count = cnts[e], off = offs[e];
    int n0 = blockIdx.x * 128;

    __shared__ short As[128 * 64];
    __shared__ short Bs[8 * 128 * 8];
    __shared__ int stok[128];

    int tid = threadIdx.x;
    if (tid < 128) {
        int p = t0 + tid;
        stok[tid] = tokl[off + (p < count ? p : count - 1)];
    }
    __syncthreads();

    int w = tid >> 6, l = tid & 63, l15 = l & 15, quad = l >> 4;
    int wm = (w >> 1) * 64, wn = (w & 1) * 64;
    int lsub = l >> 3, cs = l & 7;

    const short* gA[4];
    short* lA[4];
#pragma unroll
    for (int i = 0; i < 4; i++) {
        int m = w * 32 + i * 8 + lsub;
        int c = (cs - m) & 7;
        int gm = off + (t0 + m < count ? t0 + m : count - 1);
        gA[i] = hg + (size_t)gm * FFN + c * 8;
        lA[i] = As + w * 2048 + i * 512 + l * 8;
    }

    const short* Bpan = W2T + (size_t)e * (FFN * HID)
                      + (size_t)(n0 >> 7) * ((FFN >> 6) * 8192);
    int bo[4];
#pragma unroll
    for (int i = 0; i < 4; i++) bo[i] = (w * 4 + i) * 512 + l * 8;

    f32x4 acc[4][4];
#pragma unroll
    for (int i = 0; i < 4; i++)
#pragma unroll
        for (int j = 0; j < 4; j++) acc[i][j] = (f32x4){0.f, 0.f, 0.f, 0.f};

    for (int kt = 0; kt < FFN / 64; kt++) {
        const short* bp = Bpan + (size_t)kt * 8192;
#pragma unroll
        for (int i = 0; i < 4; i++) async_cp16(gA[i], lA[i]);
#pragma unroll
        for (int i = 0; i < 4; i++) async_cp16(bp + bo[i], Bs + bo[i]);
#pragma unroll
        for (int i = 0; i < 4; i++) gA[i] += 64;
        __syncthreads();
#pragma unroll
        for (int kk = 0; kk < 2; kk++) {
            bf16x8 a[4], b[4];
#pragma unroll
            for (int mt = 0; mt < 4; mt++) {
                int m = wm + mt * 16 + l15;
                a[mt] = *(const bf16x8*)&As[m * 64 + (((kk * 4 + quad) + m) & 7) * 8];
            }
#pragma unroll
            for (int nt = 0; nt < 4; nt++) {
                int n = wn + nt * 16 + l15;
                b[nt] = *(const bf16x8*)&Bs[(kk * 4 + quad) * 1024 + n * 8];
            }
#pragma unroll
            for (int mt = 0; mt < 4; mt++)
#pragma unroll
                for (int nt = 0; nt < 4; nt++)
                    acc[mt][nt] = __builtin_amdgcn_mfma_f32_16x16x32_bf16(
                        a[mt], b[nt], acc[mt][nt], 0, 0, 0);
        }
        __syncthreads();
    }

    const float* b2e = b2 + e * HID + n0;
#pragma unroll
    for (int mt = 0; mt < 4; mt++) {
        int rbase = wm + mt * 16 + quad * 4;
#pragma unroll
        for (int nt = 0; nt < 4; nt++) {
            int coln = wn + nt * 16 + l15;
            float bb = b2e[coln];
#pragma unroll
            for (int r = 0; r < 4; r++) {
                int p = t0 + rbase + r;
                if (p < count) {
                    int tok = stok[rbase + r];
                    out[(size_t)tok * HID + n0 + coln] = acc[mt][nt][r] + bb;
                }
            }
        }
    }
}

extern "C" void kernel_launch(void* const* d_in, const int* in_sizes, int n_in,
                              void* d_out, int out_size, void* d_ws, size_t ws_size,
                              hipStream_t stream) {
    const float* x   = (const float*)d_in[0];
    const int*   idx = (const int*)d_in[1];
    const float* W1  = (const float*)d_in[2];
    const float* b1  = (const float*)d_in[3];
    const float* W2  = (const float*)d_in[4];
    const float* b2  = (const float*)d_in[5];
    float* out = (float*)d_out;

    const size_t META = 32768;
    int*   offs    = (int*)d_ws;
    int*   cnts    = offs + 8;
    int*   tokl    = offs + 16;          // [2048]
    int*   slot_e  = offs + 16 + T_TOK;  // [MAX_SLOTS]
    int*   slot_t0 = slot_e + MAX_SLOTS;
    char*  base    = (char*)d_ws + META;
    short* xb  = (short*)base;                                    // 4 MB
    short* hg  = (short*)(base + (size_t)T_TOK * HID * 2);        // 8 MB
    short* W1T = (short*)(base + (size_t)T_TOK * HID * 2 + (size_t)T_TOK * FFN * 2);
    short* W2T = W1T + (size_t)NEXP * FFN * HID;                  // 32 MB each

    // blocks: [0,2048) W1-trans | [2048,4096) W2-trans | [4096,5120) xcvt
    //         | 5120 bucket
    prep_kernel<<<5121, 256, 0, stream>>>(
        x, idx, W1, W2, xb, W1T, W2T,
        offs, cnts, tokl, slot_e, slot_t0);

    gemm1_kernel<<<dim3(FFN / 128, MAX_SLOTS), 256, 0, stream>>>(
        xb, W1T, b1, offs, cnts, tokl, slot_e, slot_t0, hg);
    gemm2_kernel<<<dim3(HID / 128, MAX_SLOTS), 256, 0, stream>>>(
        hg, W2T, b2, offs, cnts, tokl, slot_e, slot_t0, out);
}

// Round 2
// 230.062 us; speedup vs baseline: 1.0609x; 1.0609x over previous
//
#include <hip/hip_runtime.h>

#define T_TOK 2048
#define HID   1024
#define FFN   2048
#define NEXP  8
#define MAX_SLOTS 40   // sum_e ceil(cnt_e/64) <= 2048/64 + 7 = 39

typedef __attribute__((ext_vector_type(8))) short bf16x8;
typedef __attribute__((ext_vector_type(4))) float f32x4;

__device__ __forceinline__ short f2bf(float f) {
    unsigned u = __builtin_bit_cast(unsigned, f);
    u = (u + 0x7fffu + ((u >> 16) & 1u)) >> 16;
    return (short)u;
}

__device__ __forceinline__ float gelu_exact(float x) {
    return 0.5f * x * (1.0f + erff(x * 0.70710678118654752f));
}

// async 16B global -> LDS DMA. LDS dest: wave-uniform base + lane*16.
__device__ __forceinline__ void async_cp16(const short* g, short* l) {
    __builtin_amdgcn_global_load_lds(
        (const __attribute__((address_space(1))) unsigned int*)g,
        (__attribute__((address_space(3))) unsigned int*)l, 16, 0, 0);
}

// ---- weight transpose body: W[e][K][N] f32 -> tiled bf16 panels -----------
// WT layout: [e][npanel=N/128][kpanel=K/64][kc=8][n=128][k8=8] (8192 shorts/panel)
__device__ __forceinline__ void wtrans_body(
        const float* __restrict__ W, short* __restrict__ WT,
        int K, int N, int e, int kblk, int nblk) {
    int tid = threadIdx.x;
    int w = tid >> 6, l = tid & 63;
    int kb = kblk * 32 + w * 8;               // this wave: 8 k-rows
    int n4 = nblk * 256 + l * 4;              // this lane: 4 n-cols
    const float* src = W + (size_t)e * K * N + (size_t)kb * N + n4;
    float4 v[8];
#pragma unroll
    for (int r = 0; r < 8; r++)
        v[r] = *(const float4*)(src + (size_t)r * N);
    int kpanel = kb >> 6;
    int kc = (kb >> 3) & 7;
    int npanel = n4 >> 7;
    int n_in = n4 & 127;
    int kpanels = K >> 6;
    short* dst = WT + (size_t)e * K * N
               + ((size_t)npanel * kpanels + kpanel) * 8192
               + kc * 1024 + n_in * 8;
#pragma unroll
    for (int j = 0; j < 4; j++) {
        bf16x8 o = {f2bf(((const float*)&v[0])[j]), f2bf(((const float*)&v[1])[j]),
                    f2bf(((const float*)&v[2])[j]), f2bf(((const float*)&v[3])[j]),
                    f2bf(((const float*)&v[4])[j]), f2bf(((const float*)&v[5])[j]),
                    f2bf(((const float*)&v[6])[j]), f2bf(((const float*)&v[7])[j])};
        *(bf16x8*)(dst + j * 8) = o;
    }
}

// ---- fused prep: wtrans W1 | wtrans W2 | xcvt | initout | bucket ----------
__global__ __launch_bounds__(256) void prep_kernel(
        const float* __restrict__ x, const int* __restrict__ idx,
        const float* __restrict__ b2,
        const float* __restrict__ W1, const float* __restrict__ W2,
        short* __restrict__ xb, float* __restrict__ out,
        short* __restrict__ W1T, short* __restrict__ W2T,
        int* __restrict__ offs, int* __restrict__ cnts,
        int* __restrict__ tokl,
        int* __restrict__ slot_e, int* __restrict__ slot_t0) {
    int bx = blockIdx.x;
    int tid = threadIdx.x;
    if (bx < 2048) {                       // W1: 8e x (32 kblk x 8 nblk)
        int e = bx >> 8, rem = bx & 255;
        wtrans_body(W1, W1T, HID, FFN, e, rem & 31, rem >> 5);
    } else if (bx < 4096) {                // W2: 8e x (64 kblk x 4 nblk)
        int b = bx - 2048;
        int e = b >> 8, rem = b & 255;
        wtrans_body(W2, W2T, FFN, HID, e, rem & 63, rem >> 6);
    } else if (bx < 5120) {                // x f32 -> bf16
        int i = ((bx - 4096) * 256 + tid) * 8;
        float4 v0 = *(const float4*)(x + i);
        float4 v1 = *(const float4*)(x + i + 4);
        bf16x8 r = {f2bf(v0.x), f2bf(v0.y), f2bf(v0.z), f2bf(v0.w),
                    f2bf(v1.x), f2bf(v1.y), f2bf(v1.z), f2bf(v1.w)};
        *(bf16x8*)(xb + i) = r;
    } else if (bx < 7168) {                // out[t] = b2[idx[t]]  (split-K base)
        int t = bx - 5120;
        int e = idx[t];
        ((float4*)(out + (size_t)t * HID))[tid] =
            ((const float4*)(b2 + (size_t)e * HID))[tid];
    } else {                               // bucket + slot worklist (64/slot)
        __shared__ int c[NEXP], cur[NEXP], o[NEXP];
        if (tid < NEXP) { c[tid] = 0; cur[tid] = 0; }
        __syncthreads();
        for (int t = tid; t < T_TOK; t += 256) atomicAdd(&c[idx[t]], 1);
        __syncthreads();
        if (tid == 0) {
            int s = 0;
            for (int e = 0; e < NEXP; e++) { o[e] = s; s += c[e]; }
            int ns = 0;
            for (int e = 0; e < NEXP; e++)
                for (int t0 = 0; t0 < c[e]; t0 += 64) {
                    slot_e[ns] = e; slot_t0[ns] = t0; ns++;
                }
            for (; ns < MAX_SLOTS; ns++) slot_e[ns] = -1;
        }
        __syncthreads();
        if (tid < NEXP) { offs[tid] = o[tid]; cnts[tid] = c[tid]; }
        for (int t = tid; t < T_TOK; t += 256) {
            int e = idx[t];
            int p = o[e] + atomicAdd(&cur[e], 1);
            tokl[p] = t;
        }
    }
}

// ---- GEMM1: hg = gelu(xb_gathered @ W1T + b1) ------------------------------
// block 64m x 128n, BK=64, double-buffered LDS with 1-ahead prefetch.
// 4 waves, each 32m x 64n. grid (FFN/128, MAX_SLOTS).
__global__ __launch_bounds__(256) void gemm1_kernel(
        const short* __restrict__ xb, const short* __restrict__ W1T,
        const float* __restrict__ b1,
        const int* __restrict__ offs, const int* __restrict__ cnts,
        const int* __restrict__ tokl,
        const int* __restrict__ slot_e, const int* __restrict__ slot_t0,
        short* __restrict__ hg) {
    int s = blockIdx.y;
    int e = slot_e[s];
    if (e < 0) return;
    int t0 = slot_t0[s], count = cnts[e], off = offs[e];
    int n0 = blockIdx.x * 128;

    __shared__ short As[2 * 64 * 64];    // 2 x [64m][64k], chunk-rotated rows
    __shared__ short Bs[2 * 8 * 128 * 8];// 2 x [8kc][128n][8k] panel image
    __shared__ int stok[64];

    int tid = threadIdx.x;
    if (tid < 64) {
        int p = t0 + tid;
        stok[tid] = tokl[off + (p < count ? p : count - 1)];
    }
    __syncthreads();

    int w = tid >> 6, l = tid & 63, l15 = l & 15, quad = l >> 4;
    int wm = (w >> 1) * 32, wn = (w & 1) * 64;

    // A staging: 2 instrs/thread; row m = w*16 + i*8 + (l>>3), slot chunk l&7
    int m0 = w * 16 + (l >> 3), m1 = m0 + 8;
    int cs = l & 7;
    int c0 = (cs - m0) & 7, c1 = (cs - m1) & 7;   // chunk rotation by row
    const short* gA0 = xb + (size_t)stok[m0] * HID + c0 * 8;
    const short* gA1 = xb + (size_t)stok[m1] * HID + c1 * 8;
    int aoff = w * 1024 + l * 8;

    // B staging: 4 instrs/thread covering kc {2w,2w+1} x n-halves
    const short* Bpan = W1T + (size_t)e * (HID * FFN)
                      + (size_t)(n0 >> 7) * ((HID >> 6) * 8192);
    int bo0 = (2 * w) * 1024 + l * 8;
    int bo1 = bo0 + 1024;
    int bo2 = bo0 + 512;
    int bo3 = bo1 + 512;

    auto stage = [&](int buf, int kt) {
        const short* bp = Bpan + (size_t)kt * 8192;
        short* As_b = As + buf * 4096;
        short* Bs_b = Bs + buf * 8192;
        async_cp16(gA0, As_b + aoff);
        async_cp16(gA1, As_b + aoff + 512);
        async_cp16(bp + bo0, Bs_b + bo0);
        async_cp16(bp + bo1, Bs_b + bo1);
        async_cp16(bp + bo2, Bs_b + bo2);
        async_cp16(bp + bo3, Bs_b + bo3);
        gA0 += 64; gA1 += 64;
    };

    f32x4 acc[2][4];
#pragma unroll
    for (int i = 0; i < 2; i++)
#pragma unroll
        for (int j = 0; j < 4; j++) acc[i][j] = (f32x4){0.f, 0.f, 0.f, 0.f};

    stage(0, 0);
    __syncthreads();                      // drains vmcnt(0): buf0 ready

    const int KT = HID / 64;
    for (int kt = 0; kt < KT; kt++) {
        if (kt + 1 < KT) stage((kt + 1) & 1, kt + 1);   // overlap w/ compute
        const short* As_b = As + (kt & 1) * 4096;
        const short* Bs_b = Bs + (kt & 1) * 8192;
        bf16x8 a[2][2], b[2][4];
#pragma unroll
        for (int kk = 0; kk < 2; kk++) {
#pragma unroll
            for (int mt = 0; mt < 2; mt++) {
                int m = wm + mt * 16 + l15;
                a[kk][mt] = *(const bf16x8*)&As_b[m * 64 + (((kk * 4 + quad) + m) & 7) * 8];
            }
#pragma unroll
            for (int nt = 0; nt < 4; nt++) {
                int n = wn + nt * 16 + l15;
                b[kk][nt] = *(const bf16x8*)&Bs_b[(kk * 4 + quad) * 1024 + n * 8];
            }
        }
#pragma unroll
        for (int kk = 0; kk < 2; kk++)
#pragma unroll
            for (int mt = 0; mt < 2; mt++)
#pragma unroll
                for (int nt = 0; nt < 4; nt++)
                    acc[mt][nt] = __builtin_amdgcn_mfma_f32_16x16x32_bf16(
                        a[kk][mt], b[kk][nt], acc[mt][nt], 0, 0, 0);
        __syncthreads();                  // next buf staged + this buf free
    }

    const float* b1e = b1 + e * FFN + n0;
#pragma unroll
    for (int mt = 0; mt < 2; mt++) {
        int rbase = wm + mt * 16 + quad * 4;
#pragma unroll
        for (int nt = 0; nt < 4; nt++) {
            int coln = wn + nt * 16 + l15;
            float bb = b1e[coln];
#pragma unroll
            for (int r = 0; r < 4; r++) {
                int p = t0 + rbase + r;
                if (p < count)
                    hg[(size_t)(off + p) * FFN + n0 + coln] =
                        f2bf(gelu_exact(acc[mt][nt][r] + bb));
            }
        }
    }
}

// ---- GEMM2: out[tok] += hg_gathered @ W2T  (split-K x2, atomic) ------------
// same structure as gemm1. grid (HID/128, MAX_SLOTS, 2).
__global__ __launch_bounds__(256) void gemm2_kernel(
        const short* __restrict__ hg, const short* __restrict__ W2T,
        const int* __restrict__ offs, const int* __restrict__ cnts,
        const int* __restrict__ tokl,
        const int* __restrict__ slot_e, const int* __restrict__ slot_t0,
        float* __restrict__ out) {
    int s = blockIdx.y;
    int e = slot_e[s];
    if (e < 0) return;
    int t0 = slot_t0[s], count = cnts[e], off = offs[e];
    int ks = blockIdx.z;
    int n0 = blockIdx.x * 128;

    __shared__ short As[2 * 64 * 64];
    __shared__ short Bs[2 * 8 * 128 * 8];
    __shared__ int stok[64];

    int tid = threadIdx.x;
    if (tid < 64) {
        int p = t0 + tid;
        stok[tid] = tokl[off + (p < count ? p : count - 1)];
    }
    __syncthreads();

    int w = tid >> 6, l = tid & 63, l15 = l & 15, quad = l >> 4;
    int wm = (w >> 1) * 32, wn = (w & 1) * 64;

    int m0 = w * 16 + (l >> 3), m1 = m0 + 8;
    int cs = l & 7;
    int c0 = (cs - m0) & 7, c1 = (cs - m1) & 7;
    int g0 = off + (t0 + m0 < count ? t0 + m0 : count - 1);
    int g1 = off + (t0 + m1 < count ? t0 + m1 : count - 1);
    const short* gA0 = hg + (size_t)g0 * FFN + ks * 1024 + c0 * 8;
    const short* gA1 = hg + (size_t)g1 * FFN + ks * 1024 + c1 * 8;
    int aoff = w * 1024 + l * 8;

    const short* Bpan = W2T + (size_t)e * (FFN * HID)
                      + (size_t)(n0 >> 7) * ((FFN >> 6) * 8192)
                      + (size_t)ks * 16 * 8192;
    int bo0 = (2 * w) * 1024 + l * 8;
    int bo1 = bo0 + 1024;
    int bo2 = bo0 + 512;
    int bo3 = bo1 + 512;

    auto stage = [&](int buf, int kt) {
        const short* bp = Bpan + (size_t)kt * 8192;
        short* As_b = As + buf * 4096;
        short* Bs_b = Bs + buf * 8192;
        async_cp16(gA0, As_b + aoff);
        async_cp16(gA1, As_b + aoff + 512);
        async_cp16(bp + bo0, Bs_b + bo0);
        async_cp16(bp + bo1, Bs_b + bo1);
        async_cp16(bp + bo2, Bs_b + bo2);
        async_cp16(bp + bo3, Bs_b + bo3);
        gA0 += 64; gA1 += 64;
    };

    f32x4 acc[2][4];
#pragma unroll
    for (int i = 0; i < 2; i++)
#pragma unroll
        for (int j = 0; j < 4; j++) acc[i][j] = (f32x4){0.f, 0.f, 0.f, 0.f};

    stage(0, 0);
    __syncthreads();

    const int KT = 16;
    for (int kt = 0; kt < KT; kt++) {
        if (kt + 1 < KT) stage((kt + 1) & 1, kt + 1);
        const short* As_b = As + (kt & 1) * 4096;
        const short* Bs_b = Bs + (kt & 1) * 8192;
        bf16x8 a[2][2], b[2][4];
#pragma unroll
        for (int kk = 0; kk < 2; kk++) {
#pragma unroll
            for (int mt = 0; mt < 2; mt++) {
                int m = wm + mt * 16 + l15;
                a[kk][mt] = *(const bf16x8*)&As_b[m * 64 + (((kk * 4 + quad) + m) & 7) * 8];
            }
#pragma unroll
            for (int nt = 0; nt < 4; nt++) {
                int n = wn + nt * 16 + l15;
                b[kk][nt] = *(const bf16x8*)&Bs_b[(kk * 4 + quad) * 1024 + n * 8];
            }
        }
#pragma unroll
        for (int kk = 0; kk < 2; kk++)
#pragma unroll
            for (int mt = 0; mt < 2; mt++)
#pragma unroll
                for (int nt = 0; nt < 4; nt++)
                    acc[mt][nt] = __builtin_amdgcn_mfma_f32_16x16x32_bf16(
                        a[kk][mt], b[kk][nt], acc[mt][nt], 0, 0, 0);
        __syncthreads();
    }

#pragma unroll
    for (int mt = 0; mt < 2; mt++) {
        int rbase = wm + mt * 16 + quad * 4;
#pragma unroll
        for (int nt = 0; nt < 4; nt++) {
            int coln = n0 + wn + nt * 16 + l15;
#pragma unroll
            for (int r = 0; r < 4; r++) {
                int p = t0 + rbase + r;
                if (p < count) {
                    int tok = stok[rbase + r];
                    atomicAdd(out + (size_t)tok * HID + coln, acc[mt][nt][r]);
                }
            }
        }
    }
}

extern "C" void kernel_launch(void* const* d_in, const int* in_sizes, int n_in,
                              void* d_out, int out_size, void* d_ws, size_t ws_size,
                              hipStream_t stream) {
    const float* x   = (const float*)d_in[0];
    const int*   idx = (const int*)d_in[1];
    const float* W1  = (const float*)d_in[2];
    const float* b1  = (const float*)d_in[3];
    const float* W2  = (const float*)d_in[4];
    const float* b2  = (const float*)d_in[5];
    float* out = (float*)d_out;

    const size_t META = 32768;
    int*   offs    = (int*)d_ws;
    int*   cnts    = offs + 8;
    int*   tokl    = offs + 16;          // [2048]
    int*   slot_e  = offs + 16 + T_TOK;  // [MAX_SLOTS]
    int*   slot_t0 = slot_e + MAX_SLOTS;
    char*  base    = (char*)d_ws + META;
    short* xb  = (short*)base;                                    // 4 MB
    short* hg  = (short*)(base + (size_t)T_TOK * HID * 2);        // 8 MB
    short* W1T = (short*)(base + (size_t)T_TOK * HID * 2 + (size_t)T_TOK * FFN * 2);
    short* W2T = W1T + (size_t)NEXP * FFN * HID;                  // 32 MB each

    // blocks: [0,2048) W1-trans | [2048,4096) W2-trans | [4096,5120) xcvt
    //         | [5120,7168) initout | 7168 bucket
    prep_kernel<<<7169, 256, 0, stream>>>(
        x, idx, b2, W1, W2, xb, out, W1T, W2T,
        offs, cnts, tokl, slot_e, slot_t0);

    gemm1_kernel<<<dim3(FFN / 128, MAX_SLOTS), 256, 0, stream>>>(
        xb, W1T, b1, offs, cnts, tokl, slot_e, slot_t0, hg);
    gemm2_kernel<<<dim3(HID / 128, MAX_SLOTS, 2), 256, 0, stream>>>(
        hg, W2T, offs, cnts, tokl, slot_e, slot_t0, out);
}